// Round 3
// baseline (1043.920 us; speedup 1.0000x reference)
//
#include <hip/hip_runtime.h>

#define NNODES 50000
#define NEDGES 800000
#define NGRAPH 512

// ---------- bf16 <-> fp32 helpers (internal activation storage only) ----------
static __device__ __forceinline__ float b2f(unsigned short u) {
    return __uint_as_float(((unsigned)u) << 16);
}
static __device__ __forceinline__ unsigned short f2b(float f) {
    unsigned u = __float_as_uint(f);
    unsigned r = (u + 0x7fffu + ((u >> 16) & 1u)) >> 16;  // round-nearest-even
    return (unsigned short)r;
}
static __device__ __forceinline__ float loadElem(const float* p, size_t i) { return p[i]; }
static __device__ __forceinline__ float loadElem(const unsigned short* p, size_t i) { return b2f(p[i]); }

// ---------- graph preprocessing ----------
__global__ void k_init(float* deg, int* counts, int* cursor) {
    int i = blockIdx.x * 256 + threadIdx.x;
    if (i < NNODES) { deg[i] = 1.0f; counts[i] = 0; cursor[i] = 0; }  // self-loop weight 1
}

__global__ void k_zero_gp(int* gp) {
    int i = blockIdx.x * 256 + threadIdx.x;
    if (i < NGRAPH * 512) gp[i] = 0;  // +0.0f bits; relu outputs >= 0 so int-max == float-max
}

__global__ void k_count(const int* __restrict__ ei, const float* __restrict__ ew,
                        float* deg, int* counts) {
    int e = blockIdx.x * 256 + threadIdx.x;
    if (e < NEDGES) {
        int d = ei[NEDGES + e];
        atomicAdd(&deg[d], ew[e]);
        atomicAdd(&counts[d], 1);
    }
}

__global__ void k_rsqrt(float* deg) {
    int i = blockIdx.x * 256 + threadIdx.x;
    if (i < NNODES) deg[i] = rsqrtf(deg[i]);  // deg >= 1 always (self loop)
}

// single-block exclusive scan of counts -> ofs (n+1 entries), 256 threads
__global__ void k_scan(const int* __restrict__ counts, int* __restrict__ ofs, int n) {
    __shared__ int wsum[4];
    __shared__ int carry_s;
    const int tid = threadIdx.x, lane = tid & 63, wid = tid >> 6;
    if (tid == 0) carry_s = 0;
    __syncthreads();
    for (int base = 0; base < n; base += 256) {
        int idx = base + tid;
        int v = (idx < n) ? counts[idx] : 0;
        int s = v;
        #pragma unroll
        for (int off = 1; off < 64; off <<= 1) {
            int y = __shfl_up(s, off, 64);
            if (lane >= off) s += y;
        }
        if (lane == 63) wsum[wid] = s;
        __syncthreads();
        int waveoff = 0;
        for (int w = 0; w < wid; ++w) waveoff += wsum[w];
        int carry = carry_s;
        if (idx < n) ofs[idx] = carry + waveoff + (s - v);  // exclusive
        __syncthreads();
        if (tid == 0) carry_s = carry + wsum[0] + wsum[1] + wsum[2] + wsum[3];
        __syncthreads();
    }
    if (tid == 0) ofs[n] = carry_s;
}

__global__ void k_fill(const int* __restrict__ ei, const float* __restrict__ ew,
                       const float* __restrict__ dinv, const int* __restrict__ row_ofs,
                       int* cursor, int* __restrict__ col, float* __restrict__ coef) {
    int e = blockIdx.x * 256 + threadIdx.x;
    if (e < NEDGES) {
        int s = ei[e];
        int d = ei[NEDGES + e];
        int pos = row_ofs[d] + atomicAdd(&cursor[d], 1);
        col[pos] = s;
        coef[pos] = ew[e] * dinv[s] * dinv[d];  // full symmetric norm folded in
    }
}

// ---------- aggregation: Z[i,:] = dinv[i]^2 * X[i,:] + sum_e coef_e * X[col_e,:] ----------
// XT: float (layer-1 input x) or ushort-bf16 (internal h). Output bf16.
template <typename XT>
__global__ void k_aggregate(const XT* __restrict__ X, const int* __restrict__ row_ofs,
                            const int* __restrict__ col, const float* __restrict__ coef,
                            const float* __restrict__ dinv, unsigned short* __restrict__ Z, int F) {
    const int i = blockIdx.x;
    const int t = threadIdx.x;
    const float di = dinv[i];
    float acc = di * di * loadElem(X, (size_t)i * F + t);
    const int beg = row_ofs[i], end = row_ofs[i + 1];
    for (int e = beg; e < end; ++e) {
        int s = col[e];
        float c = coef[e];
        acc += c * loadElem(X, (size_t)s * F + t);
    }
    Z[(size_t)i * F + t] = f2b(acc);
}

// ---------- tiled fp32 GEMM: C = act(A[MxK] @ W[KxN] + bias) ----------
// 64x64 tile, 256 threads, 4x4 microtile, BK=16. K%16==0, N%64==0.
// AT: ushort (bf16 activations) or float. W/bias always fp32.
// CMODE 0: store bf16 (+relu). 1: store fp32 (relu flag). 2: fused per-graph
//          relu+max-pool via int-bits atomicMax into gp[NGRAPH x N].
template <typename AT, int CMODE>
__global__ __launch_bounds__(256) void k_gemm(const AT* __restrict__ A,
                                              const float* __restrict__ W,
                                              const float* __restrict__ bias,
                                              void* __restrict__ Cv,
                                              const int* __restrict__ batch,
                                              int* __restrict__ gp,
                                              int M, int N, int K, int relu) {
    __shared__ float As[16][64];  // [k][m]
    __shared__ float Ws[16][64];  // [k][n]
    const int tid = threadIdx.x;
    const int tx = tid & 15, ty = tid >> 4;
    const int m0 = blockIdx.y * 64, n0 = blockIdx.x * 64;

    const int arow = tid >> 2;          // 0..63
    const int ka = (tid & 3) * 4;       // 0,4,8,12
    const bool arow_ok = (m0 + arow) < M;
    const size_t aoff = (size_t)(m0 + arow) * K;
    const int kw = ty;                  // 0..15
    const int wn = tx * 4;              // 0..60

    float acc[4][4] = {};

    for (int k0 = 0; k0 < K; k0 += 16) {
        float a0 = 0.f, a1 = 0.f, a2 = 0.f, a3 = 0.f;
        if (arow_ok) {
            if constexpr (sizeof(AT) == 2) {
                unsigned long long av = *(const unsigned long long*)(A + aoff + k0 + ka);
                a0 = b2f((unsigned short)(av & 0xffff));
                a1 = b2f((unsigned short)((av >> 16) & 0xffff));
                a2 = b2f((unsigned short)((av >> 32) & 0xffff));
                a3 = b2f((unsigned short)(av >> 48));
            } else {
                float4 av = *(const float4*)((const float*)A + aoff + k0 + ka);
                a0 = av.x; a1 = av.y; a2 = av.z; a3 = av.w;
            }
        }
        As[ka + 0][arow] = a0;
        As[ka + 1][arow] = a1;
        As[ka + 2][arow] = a2;
        As[ka + 3][arow] = a3;
        *(float4*)&Ws[kw][wn] = *(const float4*)(W + (size_t)(k0 + kw) * N + n0 + wn);
        __syncthreads();
        #pragma unroll
        for (int k = 0; k < 16; ++k) {
            const float4 a = *(const float4*)&As[k][ty * 4];
            const float4 w = *(const float4*)&Ws[k][tx * 4];
            acc[0][0] += a.x * w.x; acc[0][1] += a.x * w.y; acc[0][2] += a.x * w.z; acc[0][3] += a.x * w.w;
            acc[1][0] += a.y * w.x; acc[1][1] += a.y * w.y; acc[1][2] += a.y * w.z; acc[1][3] += a.y * w.w;
            acc[2][0] += a.z * w.x; acc[2][1] += a.z * w.y; acc[2][2] += a.z * w.z; acc[2][3] += a.z * w.w;
            acc[3][0] += a.w * w.x; acc[3][1] += a.w * w.y; acc[3][2] += a.w * w.z; acc[3][3] += a.w * w.w;
        }
        __syncthreads();
    }

    float bv[4];
    #pragma unroll
    for (int j = 0; j < 4; ++j) bv[j] = bias[n0 + tx * 4 + j];

    if constexpr (CMODE == 2) {
        // fused per-graph relu+max-pool (batch sorted; values >= 0 so int-max == float-max)
        int gprev = -1;
        float vmax[4] = {0.f, 0.f, 0.f, 0.f};
        for (int i = 0; i < 4; ++i) {
            int r = m0 + ty * 4 + i;
            if (r >= M) break;
            float v[4];
            #pragma unroll
            for (int j = 0; j < 4; ++j) v[j] = fmaxf(acc[i][j] + bv[j], 0.f);
            int g = batch[r];
            if (g != gprev) {
                if (gprev >= 0) {
                    #pragma unroll
                    for (int j = 0; j < 4; ++j)
                        atomicMax(&gp[(size_t)gprev * N + n0 + tx * 4 + j], __float_as_int(vmax[j]));
                }
                gprev = g;
                #pragma unroll
                for (int j = 0; j < 4; ++j) vmax[j] = v[j];
            } else {
                #pragma unroll
                for (int j = 0; j < 4; ++j) vmax[j] = fmaxf(vmax[j], v[j]);
            }
        }
        if (gprev >= 0) {
            #pragma unroll
            for (int j = 0; j < 4; ++j)
                atomicMax(&gp[(size_t)gprev * N + n0 + tx * 4 + j], __float_as_int(vmax[j]));
        }
    } else if constexpr (CMODE == 1) {
        float* C = (float*)Cv;
        #pragma unroll
        for (int i = 0; i < 4; ++i) {
            int r = m0 + ty * 4 + i;
            if (r < M) {
                float4 o;
                o.x = acc[i][0] + bv[0]; o.y = acc[i][1] + bv[1];
                o.z = acc[i][2] + bv[2]; o.w = acc[i][3] + bv[3];
                if (relu) { o.x = fmaxf(o.x, 0.f); o.y = fmaxf(o.y, 0.f); o.z = fmaxf(o.z, 0.f); o.w = fmaxf(o.w, 0.f); }
                *(float4*)(C + (size_t)r * N + n0 + tx * 4) = o;
            }
        }
    } else {
        unsigned short* C = (unsigned short*)Cv;
        #pragma unroll
        for (int i = 0; i < 4; ++i) {
            int r = m0 + ty * 4 + i;
            if (r < M) {
                unsigned long long o = 0ull;
                #pragma unroll
                for (int j = 0; j < 4; ++j) {
                    float v = acc[i][j] + bv[j];
                    if (relu) v = fmaxf(v, 0.f);
                    o |= ((unsigned long long)f2b(v)) << (16 * j);
                }
                *(unsigned long long*)(C + (size_t)r * N + n0 + tx * 4) = o;
            }
        }
    }
}

extern "C" void kernel_launch(void* const* d_in, const int* in_sizes, int n_in,
                              void* d_out, int out_size, void* d_ws, size_t ws_size,
                              hipStream_t stream) {
    const float* x   = (const float*)d_in[0];
    const float* ew  = (const float*)d_in[1];
    const float* W1  = (const float*)d_in[2];
    const float* b1  = (const float*)d_in[3];
    const float* W2  = (const float*)d_in[4];
    const float* b2  = (const float*)d_in[5];
    const float* W3  = (const float*)d_in[6];
    const float* b3  = (const float*)d_in[7];
    const float* Wf1 = (const float*)d_in[8];
    const float* bf1 = (const float*)d_in[9];
    const float* Wf2 = (const float*)d_in[10];
    const float* bf2 = (const float*)d_in[11];
    const int* ei    = (const int*)d_in[12];
    const int* batch = (const int*)d_in[13];
    float* out = (float*)d_out;
    (void)in_sizes; (void)n_in; (void)out_size; (void)ws_size;

    char* p = (char*)d_ws;
    auto alloc = [&](size_t bytes) -> char* {
        char* r = p;
        p += (bytes + 255) & ~(size_t)255;
        return r;
    };
    float* deg    = (float*)alloc((size_t)NNODES * 4);          // becomes dinv in place
    int*   counts = (int*)  alloc((size_t)NNODES * 4);
    int*   cursor = (int*)  alloc((size_t)NNODES * 4);
    int*   rowofs = (int*)  alloc((size_t)(NNODES + 1) * 4);
    int*   col    = (int*)  alloc((size_t)NEDGES * 4);
    float* coef   = (float*)alloc((size_t)NEDGES * 4);
    int*   gp     = (int*)  alloc((size_t)NGRAPH * 512 * 4);    // fp32-bit max-pool accum
    float* f1     = (float*)alloc((size_t)NGRAPH * 1024 * 4);
    unsigned short* bufA = (unsigned short*)alloc((size_t)NNODES * 256 * 2);  // bf16 activations
    unsigned short* bufB = (unsigned short*)alloc((size_t)NNODES * 256 * 2);
    // total ~62 MB (round-2's 61 MB footprint ran, so this fits)

    const int nbN = (NNODES + 255) / 256;
    const int nbE = (NEDGES + 255) / 256;
    const int nbG = (NGRAPH * 512 + 255) / 256;

    // graph preprocessing (shared by all 3 conv layers)
    k_init<<<nbN, 256, 0, stream>>>(deg, counts, cursor);
    k_zero_gp<<<nbG, 256, 0, stream>>>(gp);
    k_count<<<nbE, 256, 0, stream>>>(ei, ew, deg, counts);
    k_rsqrt<<<nbN, 256, 0, stream>>>(deg);
    k_scan<<<1, 256, 0, stream>>>(counts, rowofs, NNODES);
    k_fill<<<nbE, 256, 0, stream>>>(ei, ew, deg, rowofs, cursor, col, coef);

    // layer 1: z1 = A_norm @ x (fp32 in, bf16 out); h1 = relu(z1 @ W1 + b1) bf16
    k_aggregate<float><<<NNODES, 128, 0, stream>>>(x, rowofs, col, coef, deg, bufA, 128);
    k_gemm<unsigned short, 0><<<dim3(128 / 64, (NNODES + 63) / 64), 256, 0, stream>>>(
        bufA, W1, b1, bufB, batch, nullptr, NNODES, 128, 128, 1);
    // layer 2: z2 = A_norm @ h1; h2 = relu(z2 @ W2 + b2) [N=256] bf16
    k_aggregate<unsigned short><<<NNODES, 128, 0, stream>>>(bufB, rowofs, col, coef, deg, bufA, 128);
    k_gemm<unsigned short, 0><<<dim3(256 / 64, (NNODES + 63) / 64), 256, 0, stream>>>(
        bufA, W2, b2, bufB, batch, nullptr, NNODES, 256, 128, 1);
    // layer 3: z3 = A_norm @ h2; fused relu(z3 @ W3 + b3) + global max pool -> gp (fp32)
    k_aggregate<unsigned short><<<NNODES, 256, 0, stream>>>(bufB, rowofs, col, coef, deg, bufA, 256);
    k_gemm<unsigned short, 2><<<dim3(512 / 64, (NNODES + 63) / 64), 256, 0, stream>>>(
        bufA, W3, b3, nullptr, batch, gp, NNODES, 512, 256, 1);

    // MLP head (fp32 throughout): f1 = relu(gp @ Wf1 + bf1); out = f1 @ Wf2 + bf2
    k_gemm<float, 1><<<dim3(1024 / 64, (NGRAPH + 63) / 64), 256, 0, stream>>>(
        (const float*)gp, Wf1, bf1, f1, batch, nullptr, NGRAPH, 1024, 512, 1);
    k_gemm<float, 1><<<dim3(128 / 64, (NGRAPH + 63) / 64), 256, 0, stream>>>(
        f1, Wf2, bf2, out, batch, nullptr, NGRAPH, 128, 1024, 0);
}

// Round 4
// 844.710 us; speedup vs baseline: 1.2358x; 1.2358x over previous
//
#include <hip/hip_runtime.h>

#define NNODES 50000
#define NEDGES 800000
#define NGRAPH 512

typedef short bf16x8 __attribute__((ext_vector_type(8)));
typedef unsigned short u16x8 __attribute__((ext_vector_type(8)));
typedef float f32x4 __attribute__((ext_vector_type(4)));

// ---------- bf16 <-> fp32 helpers ----------
static __device__ __forceinline__ float b2f(unsigned short u) {
    return __uint_as_float(((unsigned)u) << 16);
}
static __device__ __forceinline__ unsigned short f2b(float f) {
    unsigned u = __float_as_uint(f);
    unsigned r = (u + 0x7fffu + ((u >> 16) & 1u)) >> 16;  // round-nearest-even
    return (unsigned short)r;
}
static __device__ __forceinline__ float loadElem(const float* p, size_t i) { return p[i]; }
static __device__ __forceinline__ float loadElem(const unsigned short* p, size_t i) { return b2f(p[i]); }

// ---------- graph preprocessing ----------
__global__ void k_init(float* deg, int* counts, int* cursor) {
    int i = blockIdx.x * 256 + threadIdx.x;
    if (i < NNODES) { deg[i] = 1.0f; counts[i] = 0; cursor[i] = 0; }  // self-loop weight 1
}

__global__ void k_zero_gp(int* gp) {
    int i = blockIdx.x * 256 + threadIdx.x;
    if (i < NGRAPH * 512) gp[i] = 0;  // +0.0f bits; relu pool >= 0 so int-max == float-max
}

__global__ void k_count(const int* __restrict__ ei, const float* __restrict__ ew,
                        float* deg, int* counts) {
    int e = blockIdx.x * 256 + threadIdx.x;
    if (e < NEDGES) {
        int d = ei[NEDGES + e];
        atomicAdd(&deg[d], ew[e]);
        atomicAdd(&counts[d], 1);
    }
}

__global__ void k_rsqrt(float* deg) {
    int i = blockIdx.x * 256 + threadIdx.x;
    if (i < NNODES) deg[i] = rsqrtf(deg[i]);
}

// single-block exclusive scan of counts -> ofs (n+1 entries)
__global__ void k_scan(const int* __restrict__ counts, int* __restrict__ ofs, int n) {
    __shared__ int wsum[4];
    __shared__ int carry_s;
    const int tid = threadIdx.x, lane = tid & 63, wid = tid >> 6;
    if (tid == 0) carry_s = 0;
    __syncthreads();
    for (int base = 0; base < n; base += 256) {
        int idx = base + tid;
        int v = (idx < n) ? counts[idx] : 0;
        int s = v;
        #pragma unroll
        for (int off = 1; off < 64; off <<= 1) {
            int y = __shfl_up(s, off, 64);
            if (lane >= off) s += y;
        }
        if (lane == 63) wsum[wid] = s;
        __syncthreads();
        int waveoff = 0;
        for (int w = 0; w < wid; ++w) waveoff += wsum[w];
        int carry = carry_s;
        if (idx < n) ofs[idx] = carry + waveoff + (s - v);
        __syncthreads();
        if (tid == 0) carry_s = carry + wsum[0] + wsum[1] + wsum[2] + wsum[3];
        __syncthreads();
    }
    if (tid == 0) ofs[n] = carry_s;
}

__global__ void k_fill(const int* __restrict__ ei, const float* __restrict__ ew,
                       const float* __restrict__ dinv, const int* __restrict__ row_ofs,
                       int* cursor, int* __restrict__ col, float* __restrict__ coef) {
    int e = blockIdx.x * 256 + threadIdx.x;
    if (e < NEDGES) {
        int s = ei[e];
        int d = ei[NEDGES + e];
        int pos = row_ofs[d] + atomicAdd(&cursor[d], 1);
        col[pos] = s;
        coef[pos] = ew[e] * dinv[s] * dinv[d];
    }
}

// weight convert+transpose: W[K][N] fp32 -> WT[N][K] bf16. N = 1<<nshift.
__global__ void k_wt(const float* __restrict__ W, unsigned short* __restrict__ WT,
                     int K, int nshift) {
    int i = blockIdx.x * 256 + threadIdx.x;  // i = k*N + n
    int N = 1 << nshift;
    if (i < (K << nshift)) {
        int k = i >> nshift, n = i & (N - 1);
        WT[(size_t)n * K + k] = f2b(W[i]);
    }
}

// ---------- aggregation: Z[i,:] = dinv[i]^2 * X[i,:] + sum_e coef_e * X[col_e,:] ----------
template <typename XT>
__global__ void k_aggregate(const XT* __restrict__ X, const int* __restrict__ row_ofs,
                            const int* __restrict__ col, const float* __restrict__ coef,
                            const float* __restrict__ dinv, unsigned short* __restrict__ Z, int F) {
    const int i = blockIdx.x;
    const int t = threadIdx.x;
    const float di = dinv[i];
    float acc = di * di * loadElem(X, (size_t)i * F + t);
    const int beg = row_ofs[i], end = row_ofs[i + 1];
    for (int e = beg; e < end; ++e) {
        int s = col[e];
        float c = coef[e];
        acc += c * loadElem(X, (size_t)s * F + t);
    }
    Z[(size_t)i * F + t] = f2b(acc);
}

// ---------- bf16 MFMA GEMM: C = relu(A[MxK] @ WT[NxK]^T + bias) ----------
// block 64(M) x 128(N), 4 waves (2x2 of 32x64), BK=32, 16x16x32 MFMA.
// CMODE 0: store bf16 (relu). CMODE 2: fused per-graph relu+max-pool into gp.
template <int CMODE>
__global__ __launch_bounds__(256) void k_gemm_mfma(const unsigned short* __restrict__ A,
                                                   const unsigned short* __restrict__ WT,
                                                   const float* __restrict__ bias,
                                                   unsigned short* __restrict__ C,
                                                   const int* __restrict__ batch,
                                                   int* __restrict__ gp,
                                                   int M, int N, int K) {
    constexpr int LDK = 40;  // padded stride (shorts): 80B rows -> 2-way bank alias (free)
    __shared__ unsigned short As[64 * LDK];
    __shared__ unsigned short Bs[128 * LDK];
    const int tid = threadIdx.x;
    const int m0 = blockIdx.y * 64, n0 = blockIdx.x * 128;
    const int wave = tid >> 6, lane = tid & 63;
    const int wm = (wave >> 1) * 32;   // wave m-offset: 0/32
    const int wn = (wave & 1) * 64;    // wave n-offset: 0/64
    const int quad = lane >> 4, mrow = lane & 15;

    // staging: 16B (8 shorts) per thread; A 64 rows, B 128 rows (2 passes)
    const int ar = tid >> 2;
    const int ak = (tid & 3) * 8;
    const bool arow_ok = (m0 + ar) < M;
    const unsigned short* Ag  = A  + (size_t)(m0 + ar) * K + ak;
    const unsigned short* Bg0 = WT + (size_t)(n0 + ar) * K + ak;
    const unsigned short* Bg1 = WT + (size_t)(n0 + ar + 64) * K + ak;

    f32x4 acc[2][4] = {};

    for (int k0 = 0; k0 < K; k0 += 32) {
        u16x8 av = {};
        if (arow_ok) av = *(const u16x8*)(Ag + k0);
        u16x8 bv0 = *(const u16x8*)(Bg0 + k0);
        u16x8 bv1 = *(const u16x8*)(Bg1 + k0);
        *(u16x8*)&As[ar * LDK + ak] = av;
        *(u16x8*)&Bs[ar * LDK + ak] = bv0;
        *(u16x8*)&Bs[(ar + 64) * LDK + ak] = bv1;
        __syncthreads();
        bf16x8 af[2], bf[4];
        #pragma unroll
        for (int mt = 0; mt < 2; ++mt)
            af[mt] = *(const bf16x8*)&As[(wm + mt * 16 + mrow) * LDK + quad * 8];
        #pragma unroll
        for (int nt = 0; nt < 4; ++nt)
            bf[nt] = *(const bf16x8*)&Bs[(wn + nt * 16 + mrow) * LDK + quad * 8];
        #pragma unroll
        for (int mt = 0; mt < 2; ++mt)
            #pragma unroll
            for (int nt = 0; nt < 4; ++nt)
                acc[mt][nt] = __builtin_amdgcn_mfma_f32_16x16x32_bf16(af[mt], bf[nt], acc[mt][nt], 0, 0, 0);
        __syncthreads();
    }

    float bn[4];
    #pragma unroll
    for (int nt = 0; nt < 4; ++nt) bn[nt] = bias[n0 + wn + nt * 16 + mrow];

    if constexpr (CMODE == 0) {
        #pragma unroll
        for (int mt = 0; mt < 2; ++mt) {
            #pragma unroll
            for (int r = 0; r < 4; ++r) {
                int row = m0 + wm + mt * 16 + quad * 4 + r;
                if (row < M) {
                    #pragma unroll
                    for (int nt = 0; nt < 4; ++nt) {
                        float v = fmaxf(acc[mt][nt][r] + bn[nt], 0.f);
                        C[(size_t)row * N + n0 + wn + nt * 16 + mrow] = f2b(v);
                    }
                }
            }
        }
    } else {
        // fused pool: block's 64 rows span <=2 graphs (min graph size 97)
        __shared__ float pools[2][2][128];
        const int g0 = batch[m0];
        int last = m0 + 63; if (last >= M) last = M - 1;
        const int gl = batch[last];
        int   gid[8];
        bool  rok[8];
        #pragma unroll
        for (int mt = 0; mt < 2; ++mt)
            #pragma unroll
            for (int r = 0; r < 4; ++r) {
                int row = m0 + wm + mt * 16 + quad * 4 + r;
                rok[mt * 4 + r] = row < M;
                gid[mt * 4 + r] = (row < M) ? batch[row] : -1;
            }
        #pragma unroll
        for (int nt = 0; nt < 4; ++nt) {
            float v0 = 0.f, v1 = 0.f;
            #pragma unroll
            for (int mt = 0; mt < 2; ++mt)
                #pragma unroll
                for (int r = 0; r < 4; ++r) {
                    if (rok[mt * 4 + r]) {
                        float v = fmaxf(acc[mt][nt][r] + bn[nt], 0.f);
                        if (gid[mt * 4 + r] == g0) v0 = fmaxf(v0, v);
                        else v1 = fmaxf(v1, v);
                    }
                }
            v0 = fmaxf(v0, __shfl_xor(v0, 16, 64));
            v0 = fmaxf(v0, __shfl_xor(v0, 32, 64));
            v1 = fmaxf(v1, __shfl_xor(v1, 16, 64));
            v1 = fmaxf(v1, __shfl_xor(v1, 32, 64));
            if (quad == 0) {
                int c = wn + nt * 16 + mrow;
                pools[wm >> 5][0][c] = v0;
                pools[wm >> 5][1][c] = v1;
            }
        }
        __syncthreads();
        int c = tid & 127, gi = tid >> 7;
        float v = fmaxf(pools[0][gi][c], pools[1][gi][c]);
        int g = gi ? gl : g0;
        if (gi == 0 || gl != g0)
            atomicMax(&gp[(size_t)g * N + n0 + c], __float_as_int(v));
    }
}

// ---------- fp32 tiled GEMM (FC head): C = act(A @ W + bias), all fp32 ----------
__global__ __launch_bounds__(256) void k_gemm_fc(const float* __restrict__ A,
                                                 const float* __restrict__ W,
                                                 const float* __restrict__ bias,
                                                 float* __restrict__ C,
                                                 int M, int N, int K, int relu) {
    __shared__ float As[16][64];
    __shared__ float Ws[16][64];
    const int tid = threadIdx.x;
    const int tx = tid & 15, ty = tid >> 4;
    const int m0 = blockIdx.y * 64, n0 = blockIdx.x * 64;
    const int arow = tid >> 2;
    const int ka = (tid & 3) * 4;
    const bool arow_ok = (m0 + arow) < M;
    const size_t aoff = (size_t)(m0 + arow) * K;
    float acc[4][4] = {};
    for (int k0 = 0; k0 < K; k0 += 16) {
        float4 av = make_float4(0.f, 0.f, 0.f, 0.f);
        if (arow_ok) av = *(const float4*)(A + aoff + k0 + ka);
        As[ka + 0][arow] = av.x; As[ka + 1][arow] = av.y;
        As[ka + 2][arow] = av.z; As[ka + 3][arow] = av.w;
        *(float4*)&Ws[ty][tx * 4] = *(const float4*)(W + (size_t)(k0 + ty) * N + n0 + tx * 4);
        __syncthreads();
        #pragma unroll
        for (int k = 0; k < 16; ++k) {
            const float4 a = *(const float4*)&As[k][ty * 4];
            const float4 w = *(const float4*)&Ws[k][tx * 4];
            acc[0][0] += a.x * w.x; acc[0][1] += a.x * w.y; acc[0][2] += a.x * w.z; acc[0][3] += a.x * w.w;
            acc[1][0] += a.y * w.x; acc[1][1] += a.y * w.y; acc[1][2] += a.y * w.z; acc[1][3] += a.y * w.w;
            acc[2][0] += a.z * w.x; acc[2][1] += a.z * w.y; acc[2][2] += a.z * w.z; acc[2][3] += a.z * w.w;
            acc[3][0] += a.w * w.x; acc[3][1] += a.w * w.y; acc[3][2] += a.w * w.z; acc[3][3] += a.w * w.w;
        }
        __syncthreads();
    }
    float bv[4];
    #pragma unroll
    for (int j = 0; j < 4; ++j) bv[j] = bias[n0 + tx * 4 + j];
    #pragma unroll
    for (int i = 0; i < 4; ++i) {
        int r = m0 + ty * 4 + i;
        if (r < M) {
            float4 o;
            o.x = acc[i][0] + bv[0]; o.y = acc[i][1] + bv[1];
            o.z = acc[i][2] + bv[2]; o.w = acc[i][3] + bv[3];
            if (relu) { o.x = fmaxf(o.x, 0.f); o.y = fmaxf(o.y, 0.f); o.z = fmaxf(o.z, 0.f); o.w = fmaxf(o.w, 0.f); }
            *(float4*)(C + (size_t)r * N + n0 + tx * 4) = o;
        }
    }
}

extern "C" void kernel_launch(void* const* d_in, const int* in_sizes, int n_in,
                              void* d_out, int out_size, void* d_ws, size_t ws_size,
                              hipStream_t stream) {
    const float* x   = (const float*)d_in[0];
    const float* ew  = (const float*)d_in[1];
    const float* W1  = (const float*)d_in[2];
    const float* b1  = (const float*)d_in[3];
    const float* W2  = (const float*)d_in[4];
    const float* b2  = (const float*)d_in[5];
    const float* W3  = (const float*)d_in[6];
    const float* b3  = (const float*)d_in[7];
    const float* Wf1 = (const float*)d_in[8];
    const float* bf1 = (const float*)d_in[9];
    const float* Wf2 = (const float*)d_in[10];
    const float* bf2 = (const float*)d_in[11];
    const int* ei    = (const int*)d_in[12];
    const int* batch = (const int*)d_in[13];
    float* out = (float*)d_out;
    (void)in_sizes; (void)n_in; (void)out_size; (void)ws_size;

    char* p = (char*)d_ws;
    auto alloc = [&](size_t bytes) -> char* {
        char* r = p;
        p += (bytes + 255) & ~(size_t)255;
        return r;
    };
    float* deg    = (float*)alloc((size_t)NNODES * 4);
    int*   counts = (int*)  alloc((size_t)NNODES * 4);
    int*   cursor = (int*)  alloc((size_t)NNODES * 4);
    int*   rowofs = (int*)  alloc((size_t)(NNODES + 1) * 4);
    int*   col    = (int*)  alloc((size_t)NEDGES * 4);
    float* coef   = (float*)alloc((size_t)NEDGES * 4);
    int*   gp     = (int*)  alloc((size_t)NGRAPH * 512 * 4);
    float* f1     = (float*)alloc((size_t)NGRAPH * 1024 * 4);
    unsigned short* wt1 = (unsigned short*)alloc((size_t)128 * 128 * 2);
    unsigned short* wt2 = (unsigned short*)alloc((size_t)256 * 128 * 2);
    unsigned short* wt3 = (unsigned short*)alloc((size_t)512 * 256 * 2);
    unsigned short* bufA = (unsigned short*)alloc((size_t)NNODES * 256 * 2);
    unsigned short* bufB = (unsigned short*)alloc((size_t)NNODES * 256 * 2);
    // total ~62.5 MB (round-3 footprint fit)

    const int nbN = (NNODES + 255) / 256;
    const int nbE = (NEDGES + 255) / 256;
    const int nbG = (NGRAPH * 512 + 255) / 256;
    const int MB = (NNODES + 63) / 64;  // 782 m-blocks

    // graph preprocessing (shared by all 3 conv layers)
    k_init<<<nbN, 256, 0, stream>>>(deg, counts, cursor);
    k_zero_gp<<<nbG, 256, 0, stream>>>(gp);
    k_count<<<nbE, 256, 0, stream>>>(ei, ew, deg, counts);
    k_rsqrt<<<nbN, 256, 0, stream>>>(deg);
    k_scan<<<1, 256, 0, stream>>>(counts, rowofs, NNODES);
    k_fill<<<nbE, 256, 0, stream>>>(ei, ew, deg, rowofs, cursor, col, coef);
    // weight bf16 transpose
    k_wt<<<(128 * 128 + 255) / 256, 256, 0, stream>>>(W1, wt1, 128, 7);
    k_wt<<<(128 * 256 + 255) / 256, 256, 0, stream>>>(W2, wt2, 128, 8);
    k_wt<<<(256 * 512 + 255) / 256, 256, 0, stream>>>(W3, wt3, 256, 9);

    // layer 1
    k_aggregate<float><<<NNODES, 128, 0, stream>>>(x, rowofs, col, coef, deg, bufA, 128);
    k_gemm_mfma<0><<<dim3(1, MB), 256, 0, stream>>>(bufA, wt1, b1, bufB, batch, nullptr, NNODES, 128, 128);
    // layer 2
    k_aggregate<unsigned short><<<NNODES, 128, 0, stream>>>(bufB, rowofs, col, coef, deg, bufA, 128);
    k_gemm_mfma<0><<<dim3(2, MB), 256, 0, stream>>>(bufA, wt2, b2, bufB, batch, nullptr, NNODES, 256, 128);
    // layer 3 + fused pool
    k_aggregate<unsigned short><<<NNODES, 256, 0, stream>>>(bufB, rowofs, col, coef, deg, bufA, 256);
    k_gemm_mfma<2><<<dim3(4, MB), 256, 0, stream>>>(bufA, wt3, b3, nullptr, batch, gp, NNODES, 512, 256);

    // MLP head (fp32)
    k_gemm_fc<<<dim3(16, (NGRAPH + 63) / 64), 256, 0, stream>>>((const float*)gp, Wf1, bf1, f1, NGRAPH, 1024, 512, 1);
    k_gemm_fc<<<dim3(2, (NGRAPH + 63) / 64), 256, 0, stream>>>(f1, Wf2, bf2, out, NGRAPH, 128, 1024, 0);
}

// Round 5
// 545.420 us; speedup vs baseline: 1.9140x; 1.5487x over previous
//
#include <hip/hip_runtime.h>

#define NNODES 50000
#define NEDGES 800000
#define NGRAPH 512

typedef short bf16x8 __attribute__((ext_vector_type(8)));
typedef unsigned short u16x8 __attribute__((ext_vector_type(8)));
typedef float f32x4 __attribute__((ext_vector_type(4)));

// ---------- bf16 <-> fp32 helpers ----------
static __device__ __forceinline__ float b2f(unsigned short u) {
    return __uint_as_float(((unsigned)u) << 16);
}
static __device__ __forceinline__ unsigned short f2b(float f) {
    unsigned u = __float_as_uint(f);
    unsigned r = (u + 0x7fffu + ((u >> 16) & 1u)) >> 16;  // round-nearest-even
    return (unsigned short)r;
}

// row-fragment loads (VEC contiguous elems at byte-aligned offsets)
static __device__ __forceinline__ void ldrow(const unsigned short* X, size_t off, float (&v)[2]) {
    unsigned u = *(const unsigned*)(X + off);
    v[0] = b2f((unsigned short)(u & 0xffff));
    v[1] = b2f((unsigned short)(u >> 16));
}
static __device__ __forceinline__ void ldrow(const unsigned short* X, size_t off, float (&v)[4]) {
    uint2 u = *(const uint2*)(X + off);
    v[0] = b2f((unsigned short)(u.x & 0xffff));
    v[1] = b2f((unsigned short)(u.x >> 16));
    v[2] = b2f((unsigned short)(u.y & 0xffff));
    v[3] = b2f((unsigned short)(u.y >> 16));
}
static __device__ __forceinline__ void ldrow(const float* X, size_t off, float (&v)[2]) {
    float2 t = *(const float2*)(X + off);
    v[0] = t.x; v[1] = t.y;
}
static __device__ __forceinline__ void ldrow(const float* X, size_t off, float (&v)[4]) {
    float4 t = *(const float4*)(X + off);
    v[0] = t.x; v[1] = t.y; v[2] = t.z; v[3] = t.w;
}

// ---------- graph preprocessing ----------
__global__ void k_init(float* deg, int* counts, int* cursor) {
    int i = blockIdx.x * 256 + threadIdx.x;
    if (i < NNODES) { deg[i] = 1.0f; counts[i] = 0; cursor[i] = 0; }  // self-loop weight 1
}

__global__ void k_zero_gp(int* gp) {
    int i = blockIdx.x * 256 + threadIdx.x;
    if (i < NGRAPH * 512) gp[i] = 0;  // +0.0f bits; relu pool >= 0 so int-max == float-max
}

__global__ void k_count(const int* __restrict__ ei, const float* __restrict__ ew,
                        float* deg, int* counts) {
    int e = blockIdx.x * 256 + threadIdx.x;
    if (e < NEDGES) {
        int d = ei[NEDGES + e];
        atomicAdd(&deg[d], ew[e]);
        atomicAdd(&counts[d], 1);
    }
}

__global__ void k_rsqrt(float* deg) {
    int i = blockIdx.x * 256 + threadIdx.x;
    if (i < NNODES) deg[i] = rsqrtf(deg[i]);
}

// ---------- 3-phase exclusive scan of counts -> ofs[n+1] ----------
// phase 1: per-block (256) local exclusive scan + block sums
__global__ void k_scan1(const int* __restrict__ counts, int* __restrict__ ofs,
                        int* __restrict__ bsum, int n) {
    __shared__ int wsum[4];
    const int tid = threadIdx.x, lane = tid & 63, wid = tid >> 6;
    const int idx = blockIdx.x * 256 + tid;
    int v = (idx < n) ? counts[idx] : 0;
    int s = v;
    #pragma unroll
    for (int off = 1; off < 64; off <<= 1) {
        int y = __shfl_up(s, off, 64);
        if (lane >= off) s += y;
    }
    if (lane == 63) wsum[wid] = s;
    __syncthreads();
    int waveoff = 0;
    for (int w = 0; w < wid; ++w) waveoff += wsum[w];
    if (idx < n) ofs[idx] = waveoff + s - v;   // block-local exclusive
    if (tid == 255) bsum[blockIdx.x] = waveoff + s;
}
// phase 2: single block scans nb (<=256) block sums in place; bsum[nb] = total
__global__ void k_scan2(int* __restrict__ bsum, int nb) {
    __shared__ int wsum[4];
    const int tid = threadIdx.x, lane = tid & 63, wid = tid >> 6;
    int v = (tid < nb) ? bsum[tid] : 0;
    int s = v;
    #pragma unroll
    for (int off = 1; off < 64; off <<= 1) {
        int y = __shfl_up(s, off, 64);
        if (lane >= off) s += y;
    }
    if (lane == 63) wsum[wid] = s;
    __syncthreads();
    int waveoff = 0;
    for (int w = 0; w < wid; ++w) waveoff += wsum[w];
    if (tid < nb) bsum[tid] = waveoff + s - v;  // exclusive
    if (tid == 255) bsum[nb] = waveoff + s;     // grand total
}
// phase 3: add block offsets; write ofs[n]
__global__ void k_scan3(int* __restrict__ ofs, const int* __restrict__ bsum, int n) {
    const int idx = blockIdx.x * 256 + threadIdx.x;
    if (idx < n) ofs[idx] += bsum[blockIdx.x];
    if (idx == 0) ofs[n] = bsum[gridDim.x];
}

__global__ void k_fill(const int* __restrict__ ei, const float* __restrict__ ew,
                       const float* __restrict__ dinv, const int* __restrict__ row_ofs,
                       int* cursor, int* __restrict__ col, float* __restrict__ coef) {
    int e = blockIdx.x * 256 + threadIdx.x;
    if (e < NEDGES) {
        int s = ei[e];
        int d = ei[NEDGES + e];
        int pos = row_ofs[d] + atomicAdd(&cursor[d], 1);
        col[pos] = s;
        coef[pos] = ew[e] * dinv[s] * dinv[d];
    }
}

// weight convert+transpose: W[K][N] fp32 -> WT[N][K] bf16. N = 1<<nshift.
__global__ void k_wt(const float* __restrict__ W, unsigned short* __restrict__ WT,
                     int K, int nshift) {
    int i = blockIdx.x * 256 + threadIdx.x;  // i = k*N + n
    int N = 1 << nshift;
    if (i < (K << nshift)) {
        int k = i >> nshift, n = i & (N - 1);
        WT[(size_t)n * K + k] = f2b(W[i]);
    }
}

// ---------- aggregation: Z[i,:] = dinv[i]^2 * X[i,:] + sum_e coef_e * X[col_e,:] ----------
// wave-per-node, lane owns VEC contiguous elems (F = 64*VEC), edge loop unrolled x4.
template <typename XT, int VEC>
__global__ __launch_bounds__(256) void k_aggregate(const XT* __restrict__ X,
                                                   const int* __restrict__ row_ofs,
                                                   const int* __restrict__ col,
                                                   const float* __restrict__ coef,
                                                   const float* __restrict__ dinv,
                                                   unsigned short* __restrict__ Z) {
    const int F = 64 * VEC;
    const int wave = threadIdx.x >> 6, lane = threadIdx.x & 63;
    const int node = blockIdx.x * 4 + wave;
    if (node >= NNODES) return;
    const int fo = lane * VEC;
    const float di = dinv[node];

    float acc[VEC], v[VEC];
    ldrow(X, (size_t)node * F + fo, v);
    #pragma unroll
    for (int j = 0; j < VEC; ++j) acc[j] = di * di * v[j];

    int e = row_ofs[node];
    const int end = row_ofs[node + 1];
    for (; e + 4 <= end; e += 4) {
        int s0 = col[e], s1 = col[e + 1], s2 = col[e + 2], s3 = col[e + 3];
        float c0 = coef[e], c1 = coef[e + 1], c2 = coef[e + 2], c3 = coef[e + 3];
        float v0[VEC], v1[VEC], v2[VEC], v3[VEC];
        ldrow(X, (size_t)s0 * F + fo, v0);
        ldrow(X, (size_t)s1 * F + fo, v1);
        ldrow(X, (size_t)s2 * F + fo, v2);
        ldrow(X, (size_t)s3 * F + fo, v3);
        #pragma unroll
        for (int j = 0; j < VEC; ++j)
            acc[j] += c0 * v0[j] + c1 * v1[j] + c2 * v2[j] + c3 * v3[j];
    }
    for (; e < end; ++e) {
        float c = coef[e];
        ldrow(X, (size_t)col[e] * F + fo, v);
        #pragma unroll
        for (int j = 0; j < VEC; ++j) acc[j] += c * v[j];
    }

    if constexpr (VEC == 2) {
        unsigned o = (unsigned)f2b(acc[0]) | ((unsigned)f2b(acc[1]) << 16);
        *(unsigned*)(Z + (size_t)node * F + fo) = o;
    } else {
        uint2 o;
        o.x = (unsigned)f2b(acc[0]) | ((unsigned)f2b(acc[1]) << 16);
        o.y = (unsigned)f2b(acc[2]) | ((unsigned)f2b(acc[3]) << 16);
        *(uint2*)(Z + (size_t)node * F + fo) = o;
    }
}

// ---------- bf16 MFMA GEMM: C = relu(A[MxK] @ WT[NxK]^T + bias) ----------
// block 64(M) x 128(N), 4 waves (2x2 of 32x64), BK=32, 16x16x32 MFMA.
// CMODE 0: store bf16 (relu). CMODE 2: fused per-graph relu+max-pool into gp.
template <int CMODE>
__global__ __launch_bounds__(256) void k_gemm_mfma(const unsigned short* __restrict__ A,
                                                   const unsigned short* __restrict__ WT,
                                                   const float* __restrict__ bias,
                                                   unsigned short* __restrict__ C,
                                                   const int* __restrict__ batch,
                                                   int* __restrict__ gp,
                                                   int M, int N, int K) {
    constexpr int LDK = 40;  // padded stride (shorts): 2-way bank alias (free)
    __shared__ unsigned short As[64 * LDK];
    __shared__ unsigned short Bs[128 * LDK];
    const int tid = threadIdx.x;
    const int m0 = blockIdx.y * 64, n0 = blockIdx.x * 128;
    const int wave = tid >> 6, lane = tid & 63;
    const int wm = (wave >> 1) * 32;
    const int wn = (wave & 1) * 64;
    const int quad = lane >> 4, mrow = lane & 15;

    const int ar = tid >> 2;
    const int ak = (tid & 3) * 8;
    const bool arow_ok = (m0 + ar) < M;
    const unsigned short* Ag  = A  + (size_t)(m0 + ar) * K + ak;
    const unsigned short* Bg0 = WT + (size_t)(n0 + ar) * K + ak;
    const unsigned short* Bg1 = WT + (size_t)(n0 + ar + 64) * K + ak;

    f32x4 acc[2][4] = {};

    for (int k0 = 0; k0 < K; k0 += 32) {
        u16x8 av = {};
        if (arow_ok) av = *(const u16x8*)(Ag + k0);
        u16x8 bv0 = *(const u16x8*)(Bg0 + k0);
        u16x8 bv1 = *(const u16x8*)(Bg1 + k0);
        *(u16x8*)&As[ar * LDK + ak] = av;
        *(u16x8*)&Bs[ar * LDK + ak] = bv0;
        *(u16x8*)&Bs[(ar + 64) * LDK + ak] = bv1;
        __syncthreads();
        bf16x8 af[2], bf[4];
        #pragma unroll
        for (int mt = 0; mt < 2; ++mt)
            af[mt] = *(const bf16x8*)&As[(wm + mt * 16 + mrow) * LDK + quad * 8];
        #pragma unroll
        for (int nt = 0; nt < 4; ++nt)
            bf[nt] = *(const bf16x8*)&Bs[(wn + nt * 16 + mrow) * LDK + quad * 8];
        #pragma unroll
        for (int mt = 0; mt < 2; ++mt)
            #pragma unroll
            for (int nt = 0; nt < 4; ++nt)
                acc[mt][nt] = __builtin_amdgcn_mfma_f32_16x16x32_bf16(af[mt], bf[nt], acc[mt][nt], 0, 0, 0);
        __syncthreads();
    }

    float bn[4];
    #pragma unroll
    for (int nt = 0; nt < 4; ++nt) bn[nt] = bias[n0 + wn + nt * 16 + mrow];

    if constexpr (CMODE == 0) {
        #pragma unroll
        for (int mt = 0; mt < 2; ++mt) {
            #pragma unroll
            for (int r = 0; r < 4; ++r) {
                int row = m0 + wm + mt * 16 + quad * 4 + r;
                if (row < M) {
                    #pragma unroll
                    for (int nt = 0; nt < 4; ++nt) {
                        float v = fmaxf(acc[mt][nt][r] + bn[nt], 0.f);
                        C[(size_t)row * N + n0 + wn + nt * 16 + mrow] = f2b(v);
                    }
                }
            }
        }
    } else {
        // fused pool: block's 64 rows span <=2 graphs (min graph size 97)
        __shared__ float pools[2][2][128];
        const int g0 = batch[m0];
        int last = m0 + 63; if (last >= M) last = M - 1;
        const int gl = batch[last];
        int  gid[8];
        bool rok[8];
        #pragma unroll
        for (int mt = 0; mt < 2; ++mt)
            #pragma unroll
            for (int r = 0; r < 4; ++r) {
                int row = m0 + wm + mt * 16 + quad * 4 + r;
                rok[mt * 4 + r] = row < M;
                gid[mt * 4 + r] = (row < M) ? batch[row] : -1;
            }
        #pragma unroll
        for (int nt = 0; nt < 4; ++nt) {
            float v0 = 0.f, v1 = 0.f;
            #pragma unroll
            for (int mt = 0; mt < 2; ++mt)
                #pragma unroll
                for (int r = 0; r < 4; ++r) {
                    if (rok[mt * 4 + r]) {
                        float v = fmaxf(acc[mt][nt][r] + bn[nt], 0.f);
                        if (gid[mt * 4 + r] == g0) v0 = fmaxf(v0, v);
                        else v1 = fmaxf(v1, v);
                    }
                }
            v0 = fmaxf(v0, __shfl_xor(v0, 16, 64));
            v0 = fmaxf(v0, __shfl_xor(v0, 32, 64));
            v1 = fmaxf(v1, __shfl_xor(v1, 16, 64));
            v1 = fmaxf(v1, __shfl_xor(v1, 32, 64));
            if (quad == 0) {
                int c = wn + nt * 16 + mrow;
                pools[wm >> 5][0][c] = v0;
                pools[wm >> 5][1][c] = v1;
            }
        }
        __syncthreads();
        int c = tid & 127, gi = tid >> 7;
        float v = fmaxf(pools[0][gi][c], pools[1][gi][c]);
        int g = gi ? gl : g0;
        if (gi == 0 || gl != g0)
            atomicMax(&gp[(size_t)g * N + n0 + c], __float_as_int(v));
    }
}

// ---------- fp32 tiled GEMM (FC head) ----------
__global__ __launch_bounds__(256) void k_gemm_fc(const float* __restrict__ A,
                                                 const float* __restrict__ W,
                                                 const float* __restrict__ bias,
                                                 float* __restrict__ C,
                                                 int M, int N, int K, int relu) {
    __shared__ float As[16][64];
    __shared__ float Ws[16][64];
    const int tid = threadIdx.x;
    const int tx = tid & 15, ty = tid >> 4;
    const int m0 = blockIdx.y * 64, n0 = blockIdx.x * 64;
    const int arow = tid >> 2;
    const int ka = (tid & 3) * 4;
    const bool arow_ok = (m0 + arow) < M;
    const size_t aoff = (size_t)(m0 + arow) * K;
    float acc[4][4] = {};
    for (int k0 = 0; k0 < K; k0 += 16) {
        float4 av = make_float4(0.f, 0.f, 0.f, 0.f);
        if (arow_ok) av = *(const float4*)(A + aoff + k0 + ka);
        As[ka + 0][arow] = av.x; As[ka + 1][arow] = av.y;
        As[ka + 2][arow] = av.z; As[ka + 3][arow] = av.w;
        *(float4*)&Ws[ty][tx * 4] = *(const float4*)(W + (size_t)(k0 + ty) * N + n0 + tx * 4);
        __syncthreads();
        #pragma unroll
        for (int k = 0; k < 16; ++k) {
            const float4 a = *(const float4*)&As[k][ty * 4];
            const float4 w = *(const float4*)&Ws[k][tx * 4];
            acc[0][0] += a.x * w.x; acc[0][1] += a.x * w.y; acc[0][2] += a.x * w.z; acc[0][3] += a.x * w.w;
            acc[1][0] += a.y * w.x; acc[1][1] += a.y * w.y; acc[1][2] += a.y * w.z; acc[1][3] += a.y * w.w;
            acc[2][0] += a.z * w.x; acc[2][1] += a.z * w.y; acc[2][2] += a.z * w.z; acc[2][3] += a.z * w.w;
            acc[3][0] += a.w * w.x; acc[3][1] += a.w * w.y; acc[3][2] += a.w * w.z; acc[3][3] += a.w * w.w;
        }
        __syncthreads();
    }
    float bv[4];
    #pragma unroll
    for (int j = 0; j < 4; ++j) bv[j] = bias[n0 + tx * 4 + j];
    #pragma unroll
    for (int i = 0; i < 4; ++i) {
        int r = m0 + ty * 4 + i;
        if (r < M) {
            float4 o;
            o.x = acc[i][0] + bv[0]; o.y = acc[i][1] + bv[1];
            o.z = acc[i][2] + bv[2]; o.w = acc[i][3] + bv[3];
            if (relu) { o.x = fmaxf(o.x, 0.f); o.y = fmaxf(o.y, 0.f); o.z = fmaxf(o.z, 0.f); o.w = fmaxf(o.w, 0.f); }
            *(float4*)(C + (size_t)r * N + n0 + tx * 4) = o;
        }
    }
}

extern "C" void kernel_launch(void* const* d_in, const int* in_sizes, int n_in,
                              void* d_out, int out_size, void* d_ws, size_t ws_size,
                              hipStream_t stream) {
    const float* x   = (const float*)d_in[0];
    const float* ew  = (const float*)d_in[1];
    const float* W1  = (const float*)d_in[2];
    const float* b1  = (const float*)d_in[3];
    const float* W2  = (const float*)d_in[4];
    const float* b2  = (const float*)d_in[5];
    const float* W3  = (const float*)d_in[6];
    const float* b3  = (const float*)d_in[7];
    const float* Wf1 = (const float*)d_in[8];
    const float* bf1 = (const float*)d_in[9];
    const float* Wf2 = (const float*)d_in[10];
    const float* bf2 = (const float*)d_in[11];
    const int* ei    = (const int*)d_in[12];
    const int* batch = (const int*)d_in[13];
    float* out = (float*)d_out;
    (void)in_sizes; (void)n_in; (void)out_size; (void)ws_size;

    char* p = (char*)d_ws;
    auto alloc = [&](size_t bytes) -> char* {
        char* r = p;
        p += (bytes + 255) & ~(size_t)255;
        return r;
    };
    const int nbN = (NNODES + 255) / 256;   // 196
    float* deg    = (float*)alloc((size_t)NNODES * 4);
    int*   counts = (int*)  alloc((size_t)NNODES * 4);
    int*   cursor = (int*)  alloc((size_t)NNODES * 4);
    int*   rowofs = (int*)  alloc((size_t)(NNODES + 1) * 4);
    int*   bsum   = (int*)  alloc((size_t)(nbN + 1) * 4);
    int*   col    = (int*)  alloc((size_t)NEDGES * 4);
    float* coef   = (float*)alloc((size_t)NEDGES * 4);
    int*   gp     = (int*)  alloc((size_t)NGRAPH * 512 * 4);
    float* f1     = (float*)alloc((size_t)NGRAPH * 1024 * 4);
    unsigned short* wt1 = (unsigned short*)alloc((size_t)128 * 128 * 2);
    unsigned short* wt2 = (unsigned short*)alloc((size_t)256 * 128 * 2);
    unsigned short* wt3 = (unsigned short*)alloc((size_t)512 * 256 * 2);
    unsigned short* bufA = (unsigned short*)alloc((size_t)NNODES * 256 * 2);
    unsigned short* bufB = (unsigned short*)alloc((size_t)NNODES * 256 * 2);

    const int nbE = (NEDGES + 255) / 256;
    const int nbG = (NGRAPH * 512 + 255) / 256;
    const int MB = (NNODES + 63) / 64;
    const int AGG = (NNODES + 3) / 4;

    // graph preprocessing (shared by all 3 conv layers)
    k_init<<<nbN, 256, 0, stream>>>(deg, counts, cursor);
    k_zero_gp<<<nbG, 256, 0, stream>>>(gp);
    k_count<<<nbE, 256, 0, stream>>>(ei, ew, deg, counts);
    k_rsqrt<<<nbN, 256, 0, stream>>>(deg);
    k_scan1<<<nbN, 256, 0, stream>>>(counts, rowofs, bsum, NNODES);
    k_scan2<<<1, 256, 0, stream>>>(bsum, nbN);
    k_scan3<<<nbN, 256, 0, stream>>>(rowofs, bsum, NNODES);
    k_fill<<<nbE, 256, 0, stream>>>(ei, ew, deg, rowofs, cursor, col, coef);
    // weight bf16 transpose
    k_wt<<<(128 * 128 + 255) / 256, 256, 0, stream>>>(W1, wt1, 128, 7);
    k_wt<<<(128 * 256 + 255) / 256, 256, 0, stream>>>(W2, wt2, 128, 8);
    k_wt<<<(256 * 512 + 255) / 256, 256, 0, stream>>>(W3, wt3, 256, 9);

    // layer 1
    k_aggregate<float, 2><<<AGG, 256, 0, stream>>>(x, rowofs, col, coef, deg, bufA);
    k_gemm_mfma<0><<<dim3(1, MB), 256, 0, stream>>>(bufA, wt1, b1, bufB, batch, nullptr, NNODES, 128, 128);
    // layer 2
    k_aggregate<unsigned short, 2><<<AGG, 256, 0, stream>>>(bufB, rowofs, col, coef, deg, bufA);
    k_gemm_mfma<0><<<dim3(2, MB), 256, 0, stream>>>(bufA, wt2, b2, bufB, batch, nullptr, NNODES, 256, 128);
    // layer 3 + fused pool
    k_aggregate<unsigned short, 4><<<AGG, 256, 0, stream>>>(bufB, rowofs, col, coef, deg, bufA);
    k_gemm_mfma<2><<<dim3(4, MB), 256, 0, stream>>>(bufA, wt3, b3, nullptr, batch, gp, NNODES, 512, 256);

    // MLP head (fp32)
    k_gemm_fc<<<dim3(16, (NGRAPH + 63) / 64), 256, 0, stream>>>((const float*)gp, Wf1, bf1, f1, NGRAPH, 1024, 512, 1);
    k_gemm_fc<<<dim3(2, (NGRAPH + 63) / 64), 256, 0, stream>>>(f1, Wf2, bf2, out, NGRAPH, 128, 1024, 0);
}

// Round 6
// 439.307 us; speedup vs baseline: 2.3763x; 1.2415x over previous
//
#include <hip/hip_runtime.h>

#define NNODES 50000
#define NEDGES 800000
#define NGRAPH 512

typedef short bf16x8 __attribute__((ext_vector_type(8)));
typedef unsigned short u16x8 __attribute__((ext_vector_type(8)));
typedef float f32x4 __attribute__((ext_vector_type(4)));

// ---------- bf16 <-> fp32 helpers ----------
static __device__ __forceinline__ float b2f(unsigned short u) {
    return __uint_as_float(((unsigned)u) << 16);
}
static __device__ __forceinline__ unsigned short f2b(float f) {
    unsigned u = __float_as_uint(f);
    unsigned r = (u + 0x7fffu + ((u >> 16) & 1u)) >> 16;  // round-nearest-even
    return (unsigned short)r;
}

// row-fragment loads
static __device__ __forceinline__ void ldrow(const unsigned short* X, size_t off, float (&v)[2]) {
    unsigned u = *(const unsigned*)(X + off);
    v[0] = b2f((unsigned short)(u & 0xffff));
    v[1] = b2f((unsigned short)(u >> 16));
}
static __device__ __forceinline__ void ldrow(const unsigned short* X, size_t off, float (&v)[4]) {
    uint2 u = *(const uint2*)(X + off);
    v[0] = b2f((unsigned short)(u.x & 0xffff));
    v[1] = b2f((unsigned short)(u.x >> 16));
    v[2] = b2f((unsigned short)(u.y & 0xffff));
    v[3] = b2f((unsigned short)(u.y >> 16));
}

// ---------- graph preprocessing ----------
// deg+count packed in u64: hi32 = edge count, lo32 = 24.8... (8.24) fixed-point weighted degree.
__global__ void k_init(unsigned long long* deg_cnt, int* cursor) {
    int i = blockIdx.x * 256 + threadIdx.x;
    if (i < NNODES) { deg_cnt[i] = (unsigned long long)(1u << 24); cursor[i] = 0; }  // self-loop w=1
}

__global__ void k_zero_gp(int* gp) {
    int i = blockIdx.x * 256 + threadIdx.x;
    if (i < NGRAPH * 512) gp[i] = 0;  // +0.0f bits; relu pool >= 0 so int-max == float-max
}

__global__ void k_count(const int* __restrict__ ei, const float* __restrict__ ew,
                        unsigned long long* deg_cnt) {
    int e = blockIdx.x * 256 + threadIdx.x;
    if (e < NEDGES) {
        int d = ei[NEDGES + e];
        unsigned fixed = __float2uint_rn(ew[e] * 16777216.0f);  // 2^24; ew in [0,1)
        atomicAdd(&deg_cnt[d], ((unsigned long long)1 << 32) | fixed);
    }
}

__global__ void k_unpack(const unsigned long long* __restrict__ deg_cnt,
                         float* __restrict__ dinv, int* __restrict__ counts) {
    int i = blockIdx.x * 256 + threadIdx.x;
    if (i < NNODES) {
        unsigned long long v = deg_cnt[i];
        counts[i] = (int)(v >> 32);
        dinv[i] = rsqrtf((float)(unsigned)(v & 0xffffffffull) * 5.9604645e-8f);  // *2^-24
    }
}

// ---------- 3-phase exclusive scan of counts -> ofs[n+1] ----------
__global__ void k_scan1(const int* __restrict__ counts, int* __restrict__ ofs,
                        int* __restrict__ bsum, int n) {
    __shared__ int wsum[4];
    const int tid = threadIdx.x, lane = tid & 63, wid = tid >> 6;
    const int idx = blockIdx.x * 256 + tid;
    int v = (idx < n) ? counts[idx] : 0;
    int s = v;
    #pragma unroll
    for (int off = 1; off < 64; off <<= 1) {
        int y = __shfl_up(s, off, 64);
        if (lane >= off) s += y;
    }
    if (lane == 63) wsum[wid] = s;
    __syncthreads();
    int waveoff = 0;
    for (int w = 0; w < wid; ++w) waveoff += wsum[w];
    if (idx < n) ofs[idx] = waveoff + s - v;
    if (tid == 255) bsum[blockIdx.x] = waveoff + s;
}
__global__ void k_scan2(int* __restrict__ bsum, int nb) {
    __shared__ int wsum[4];
    const int tid = threadIdx.x, lane = tid & 63, wid = tid >> 6;
    int v = (tid < nb) ? bsum[tid] : 0;
    int s = v;
    #pragma unroll
    for (int off = 1; off < 64; off <<= 1) {
        int y = __shfl_up(s, off, 64);
        if (lane >= off) s += y;
    }
    if (lane == 63) wsum[wid] = s;
    __syncthreads();
    int waveoff = 0;
    for (int w = 0; w < wid; ++w) waveoff += wsum[w];
    if (tid < nb) bsum[tid] = waveoff + s - v;
    if (tid == 255) bsum[nb] = waveoff + s;
}
__global__ void k_scan3(int* __restrict__ ofs, const int* __restrict__ bsum, int n) {
    const int idx = blockIdx.x * 256 + threadIdx.x;
    if (idx < n) ofs[idx] += bsum[blockIdx.x];
    if (idx == 0) ofs[n] = bsum[gridDim.x];
}

__global__ void k_fill(const int* __restrict__ ei, const float* __restrict__ ew,
                       const float* __restrict__ dinv, const int* __restrict__ row_ofs,
                       int* cursor, int* __restrict__ col, float* __restrict__ coef) {
    int e = blockIdx.x * 256 + threadIdx.x;
    if (e < NEDGES) {
        int s = ei[e];
        int d = ei[NEDGES + e];
        int pos = row_ofs[d] + atomicAdd(&cursor[d], 1);
        col[pos] = s;
        coef[pos] = ew[e] * dinv[s] * dinv[d];
    }
}

// weight convert+transpose: W[K][N] fp32 -> WT[N][K] bf16. N = 1<<nshift.
__global__ void k_wt(const float* __restrict__ W, unsigned short* __restrict__ WT,
                     int K, int nshift) {
    int i = blockIdx.x * 256 + threadIdx.x;
    int N = 1 << nshift;
    if (i < (K << nshift)) {
        int k = i >> nshift, n = i & (N - 1);
        WT[(size_t)n * K + k] = f2b(W[i]);
    }
}

// fp32 -> bf16 elementwise (n4 = n/4)
__global__ void k_cvt4(const float* __restrict__ X, unsigned short* __restrict__ Y, int n4) {
    int i = blockIdx.x * 256 + threadIdx.x;
    if (i < n4) {
        float4 v = ((const float4*)X)[i];
        uint2 o;
        o.x = (unsigned)f2b(v.x) | ((unsigned)f2b(v.y) << 16);
        o.y = (unsigned)f2b(v.z) | ((unsigned)f2b(v.w) << 16);
        ((uint2*)Y)[i] = o;
    }
}

// ---------- aggregation: Z[i,:] = dinv[i]^2 * X[i,:] + sum_e coef_e * X[col_e,:] ----------
// wave-per-node, lane owns VEC contiguous elems (F = 64*VEC), edge loop unrolled x4.
template <int VEC>
__global__ __launch_bounds__(256) void k_aggregate(const unsigned short* __restrict__ X,
                                                   const int* __restrict__ row_ofs,
                                                   const int* __restrict__ col,
                                                   const float* __restrict__ coef,
                                                   const float* __restrict__ dinv,
                                                   unsigned short* __restrict__ Z) {
    const int F = 64 * VEC;
    const int wave = threadIdx.x >> 6, lane = threadIdx.x & 63;
    const int node = blockIdx.x * 4 + wave;
    if (node >= NNODES) return;
    const int fo = lane * VEC;
    const float di = dinv[node];

    float acc[VEC], v[VEC];
    ldrow(X, (size_t)node * F + fo, v);
    #pragma unroll
    for (int j = 0; j < VEC; ++j) acc[j] = di * di * v[j];

    int e = row_ofs[node];
    const int end = row_ofs[node + 1];
    for (; e + 4 <= end; e += 4) {
        int s0 = col[e], s1 = col[e + 1], s2 = col[e + 2], s3 = col[e + 3];
        float c0 = coef[e], c1 = coef[e + 1], c2 = coef[e + 2], c3 = coef[e + 3];
        float v0[VEC], v1[VEC], v2[VEC], v3[VEC];
        ldrow(X, (size_t)s0 * F + fo, v0);
        ldrow(X, (size_t)s1 * F + fo, v1);
        ldrow(X, (size_t)s2 * F + fo, v2);
        ldrow(X, (size_t)s3 * F + fo, v3);
        #pragma unroll
        for (int j = 0; j < VEC; ++j)
            acc[j] += c0 * v0[j] + c1 * v1[j] + c2 * v2[j] + c3 * v3[j];
    }
    for (; e < end; ++e) {
        float c = coef[e];
        ldrow(X, (size_t)col[e] * F + fo, v);
        #pragma unroll
        for (int j = 0; j < VEC; ++j) acc[j] += c * v[j];
    }

    if constexpr (VEC == 2) {
        unsigned o = (unsigned)f2b(acc[0]) | ((unsigned)f2b(acc[1]) << 16);
        *(unsigned*)(Z + (size_t)node * F + fo) = o;
    } else {
        uint2 o;
        o.x = (unsigned)f2b(acc[0]) | ((unsigned)f2b(acc[1]) << 16);
        o.y = (unsigned)f2b(acc[2]) | ((unsigned)f2b(acc[3]) << 16);
        *(uint2*)(Z + (size_t)node * F + fo) = o;
    }
}

// ---------- bf16 MFMA GEMM: C = epi(A[MxK] @ WT[NxK]^T + bias) ----------
// block 64(M) x 128(N), 4 waves (2x2 of 32x64), BK=32, 16x16x32 MFMA.
// CMODE 0: store bf16 + relu. 1: store fp32, no relu. 2: fused per-graph relu+max-pool into gp.
template <int CMODE>
__global__ __launch_bounds__(256) void k_gemm_mfma(const unsigned short* __restrict__ A,
                                                   const unsigned short* __restrict__ WT,
                                                   const float* __restrict__ bias,
                                                   void* __restrict__ Cv,
                                                   const int* __restrict__ batch,
                                                   int* __restrict__ gp,
                                                   int M, int N, int K) {
    constexpr int LDK = 40;  // padded stride (shorts): 2-way bank alias (free)
    __shared__ unsigned short As[64 * LDK];
    __shared__ unsigned short Bs[128 * LDK];
    const int tid = threadIdx.x;
    const int m0 = blockIdx.y * 64, n0 = blockIdx.x * 128;
    const int wave = tid >> 6, lane = tid & 63;
    const int wm = (wave >> 1) * 32;
    const int wn = (wave & 1) * 64;
    const int quad = lane >> 4, mrow = lane & 15;

    const int ar = tid >> 2;
    const int ak = (tid & 3) * 8;
    const bool arow_ok = (m0 + ar) < M;
    const unsigned short* Ag  = A  + (size_t)(m0 + ar) * K + ak;
    const unsigned short* Bg0 = WT + (size_t)(n0 + ar) * K + ak;
    const unsigned short* Bg1 = WT + (size_t)(n0 + ar + 64) * K + ak;

    f32x4 acc[2][4] = {};

    for (int k0 = 0; k0 < K; k0 += 32) {
        u16x8 av = {};
        if (arow_ok) av = *(const u16x8*)(Ag + k0);
        u16x8 bv0 = *(const u16x8*)(Bg0 + k0);
        u16x8 bv1 = *(const u16x8*)(Bg1 + k0);
        *(u16x8*)&As[ar * LDK + ak] = av;
        *(u16x8*)&Bs[ar * LDK + ak] = bv0;
        *(u16x8*)&Bs[(ar + 64) * LDK + ak] = bv1;
        __syncthreads();
        bf16x8 af[2], bf[4];
        #pragma unroll
        for (int mt = 0; mt < 2; ++mt)
            af[mt] = *(const bf16x8*)&As[(wm + mt * 16 + mrow) * LDK + quad * 8];
        #pragma unroll
        for (int nt = 0; nt < 4; ++nt)
            bf[nt] = *(const bf16x8*)&Bs[(wn + nt * 16 + mrow) * LDK + quad * 8];
        #pragma unroll
        for (int mt = 0; mt < 2; ++mt)
            #pragma unroll
            for (int nt = 0; nt < 4; ++nt)
                acc[mt][nt] = __builtin_amdgcn_mfma_f32_16x16x32_bf16(af[mt], bf[nt], acc[mt][nt], 0, 0, 0);
        __syncthreads();
    }

    float bn[4];
    #pragma unroll
    for (int nt = 0; nt < 4; ++nt) bn[nt] = bias[n0 + wn + nt * 16 + mrow];

    if constexpr (CMODE == 0) {
        unsigned short* C = (unsigned short*)Cv;
        #pragma unroll
        for (int mt = 0; mt < 2; ++mt) {
            #pragma unroll
            for (int r = 0; r < 4; ++r) {
                int row = m0 + wm + mt * 16 + quad * 4 + r;
                if (row < M) {
                    #pragma unroll
                    for (int nt = 0; nt < 4; ++nt) {
                        float v = fmaxf(acc[mt][nt][r] + bn[nt], 0.f);
                        C[(size_t)row * N + n0 + wn + nt * 16 + mrow] = f2b(v);
                    }
                }
            }
        }
    } else if constexpr (CMODE == 1) {
        float* C = (float*)Cv;
        #pragma unroll
        for (int mt = 0; mt < 2; ++mt) {
            #pragma unroll
            for (int r = 0; r < 4; ++r) {
                int row = m0 + wm + mt * 16 + quad * 4 + r;
                if (row < M) {
                    #pragma unroll
                    for (int nt = 0; nt < 4; ++nt)
                        C[(size_t)row * N + n0 + wn + nt * 16 + mrow] = acc[mt][nt][r] + bn[nt];
                }
            }
        }
    } else {
        // fused pool: block's 64 rows span <=2 graphs (min graph size 97)
        __shared__ float pools[2][2][128];
        const int g0 = batch[m0];
        int last = m0 + 63; if (last >= M) last = M - 1;
        const int gl = batch[last];
        int  gid[8];
        bool rok[8];
        #pragma unroll
        for (int mt = 0; mt < 2; ++mt)
            #pragma unroll
            for (int r = 0; r < 4; ++r) {
                int row = m0 + wm + mt * 16 + quad * 4 + r;
                rok[mt * 4 + r] = row < M;
                gid[mt * 4 + r] = (row < M) ? batch[row] : -1;
            }
        #pragma unroll
        for (int nt = 0; nt < 4; ++nt) {
            float v0 = 0.f, v1 = 0.f;
            #pragma unroll
            for (int mt = 0; mt < 2; ++mt)
                #pragma unroll
                for (int r = 0; r < 4; ++r) {
                    if (rok[mt * 4 + r]) {
                        float v = fmaxf(acc[mt][nt][r] + bn[nt], 0.f);
                        if (gid[mt * 4 + r] == g0) v0 = fmaxf(v0, v);
                        else v1 = fmaxf(v1, v);
                    }
                }
            v0 = fmaxf(v0, __shfl_xor(v0, 16, 64));
            v0 = fmaxf(v0, __shfl_xor(v0, 32, 64));
            v1 = fmaxf(v1, __shfl_xor(v1, 16, 64));
            v1 = fmaxf(v1, __shfl_xor(v1, 32, 64));
            if (quad == 0) {
                int c = wn + nt * 16 + mrow;
                pools[wm >> 5][0][c] = v0;
                pools[wm >> 5][1][c] = v1;
            }
        }
        __syncthreads();
        int c = tid & 127, gi = tid >> 7;
        float v = fmaxf(pools[0][gi][c], pools[1][gi][c]);
        int g = gi ? gl : g0;
        if (gi == 0 || gl != g0)
            atomicMax(&gp[(size_t)g * N + n0 + c], __float_as_int(v));
    }
}

// gp int-bits fp32 -> bf16
__global__ void k_cvt_gp(const int* __restrict__ gp, unsigned short* __restrict__ g16) {
    int i = blockIdx.x * 256 + threadIdx.x;
    if (i < NGRAPH * 512) g16[i] = f2b(__int_as_float(gp[i]));
}

extern "C" void kernel_launch(void* const* d_in, const int* in_sizes, int n_in,
                              void* d_out, int out_size, void* d_ws, size_t ws_size,
                              hipStream_t stream) {
    const float* x   = (const float*)d_in[0];
    const float* ew  = (const float*)d_in[1];
    const float* W1  = (const float*)d_in[2];
    const float* b1  = (const float*)d_in[3];
    const float* W2  = (const float*)d_in[4];
    const float* b2  = (const float*)d_in[5];
    const float* W3  = (const float*)d_in[6];
    const float* b3  = (const float*)d_in[7];
    const float* Wf1 = (const float*)d_in[8];
    const float* bf1 = (const float*)d_in[9];
    const float* Wf2 = (const float*)d_in[10];
    const float* bf2 = (const float*)d_in[11];
    const int* ei    = (const int*)d_in[12];
    const int* batch = (const int*)d_in[13];
    float* out = (float*)d_out;
    (void)in_sizes; (void)n_in; (void)out_size; (void)ws_size;

    char* p = (char*)d_ws;
    auto alloc = [&](size_t bytes) -> char* {
        char* r = p;
        p += (bytes + 255) & ~(size_t)255;
        return r;
    };
    const int nbN = (NNODES + 255) / 256;   // 196
    unsigned long long* deg_cnt = (unsigned long long*)alloc((size_t)NNODES * 8);
    float* dinv   = (float*)alloc((size_t)NNODES * 4);
    int*   counts = (int*)  alloc((size_t)NNODES * 4);
    int*   cursor = (int*)  alloc((size_t)NNODES * 4);
    int*   rowofs = (int*)  alloc((size_t)(NNODES + 1) * 4);
    int*   bsum   = (int*)  alloc((size_t)(nbN + 1) * 4);
    int*   col    = (int*)  alloc((size_t)NEDGES * 4);
    float* coef   = (float*)alloc((size_t)NEDGES * 4);
    int*   gp     = (int*)  alloc((size_t)NGRAPH * 512 * 4);
    unsigned short* gp16 = (unsigned short*)alloc((size_t)NGRAPH * 512 * 2);
    unsigned short* f1   = (unsigned short*)alloc((size_t)NGRAPH * 1024 * 2);
    unsigned short* wt1  = (unsigned short*)alloc((size_t)128 * 128 * 2);
    unsigned short* wt2  = (unsigned short*)alloc((size_t)256 * 128 * 2);
    unsigned short* wt3  = (unsigned short*)alloc((size_t)512 * 256 * 2);
    unsigned short* wtf1 = (unsigned short*)alloc((size_t)1024 * 512 * 2);
    unsigned short* wtf2 = (unsigned short*)alloc((size_t)128 * 1024 * 2);
    unsigned short* bufA = (unsigned short*)alloc((size_t)NNODES * 256 * 2);
    unsigned short* bufB = (unsigned short*)alloc((size_t)NNODES * 256 * 2);
    unsigned short* x16  = bufB;  // alias: x16 consumed by agg-1 before gemm-1 writes bufB
    // total ~63 MB

    const int nbE = (NEDGES + 255) / 256;
    const int nbG = (NGRAPH * 512 + 255) / 256;
    const int MB = (NNODES + 63) / 64;
    const int AGG = (NNODES + 3) / 4;

    // graph preprocessing (shared by all 3 conv layers)
    k_init<<<nbN, 256, 0, stream>>>(deg_cnt, cursor);
    k_zero_gp<<<nbG, 256, 0, stream>>>(gp);
    k_count<<<nbE, 256, 0, stream>>>(ei, ew, deg_cnt);
    k_unpack<<<nbN, 256, 0, stream>>>(deg_cnt, dinv, counts);
    k_scan1<<<nbN, 256, 0, stream>>>(counts, rowofs, bsum, NNODES);
    k_scan2<<<1, 256, 0, stream>>>(bsum, nbN);
    k_scan3<<<nbN, 256, 0, stream>>>(rowofs, bsum, NNODES);
    k_fill<<<nbE, 256, 0, stream>>>(ei, ew, dinv, rowofs, cursor, col, coef);
    // weight bf16 transposes
    k_wt<<<(128 * 128 + 255) / 256, 256, 0, stream>>>(W1, wt1, 128, 7);
    k_wt<<<(128 * 256 + 255) / 256, 256, 0, stream>>>(W2, wt2, 128, 8);
    k_wt<<<(256 * 512 + 255) / 256, 256, 0, stream>>>(W3, wt3, 256, 9);
    k_wt<<<(512 * 1024 + 255) / 256, 256, 0, stream>>>(Wf1, wtf1, 512, 10);
    k_wt<<<(1024 * 128 + 255) / 256, 256, 0, stream>>>(Wf2, wtf2, 1024, 7);
    // x -> bf16 (into bufB alias)
    k_cvt4<<<(NNODES * 128 / 4 + 255) / 256, 256, 0, stream>>>(x, x16, NNODES * 128 / 4);

    // layer 1
    k_aggregate<2><<<AGG, 256, 0, stream>>>(x16, rowofs, col, coef, dinv, bufA);
    k_gemm_mfma<0><<<dim3(1, MB), 256, 0, stream>>>(bufA, wt1, b1, bufB, batch, nullptr, NNODES, 128, 128);
    // layer 2
    k_aggregate<2><<<AGG, 256, 0, stream>>>(bufB, rowofs, col, coef, dinv, bufA);
    k_gemm_mfma<0><<<dim3(2, MB), 256, 0, stream>>>(bufA, wt2, b2, bufB, batch, nullptr, NNODES, 256, 128);
    // layer 3 + fused pool
    k_aggregate<4><<<AGG, 256, 0, stream>>>(bufB, rowofs, col, coef, dinv, bufA);
    k_gemm_mfma<2><<<dim3(4, MB), 256, 0, stream>>>(bufA, wt3, b3, nullptr, batch, gp, NNODES, 512, 256);

    // MLP head via MFMA (bf16 weights/activations, fp32 accumulate)
    k_cvt_gp<<<nbG, 256, 0, stream>>>(gp, gp16);
    k_gemm_mfma<0><<<dim3(8, NGRAPH / 64), 256, 0, stream>>>(gp16, wtf1, bf1, f1, batch, nullptr, NGRAPH, 1024, 512);
    k_gemm_mfma<1><<<dim3(1, NGRAPH / 64), 256, 0, stream>>>(f1, wtf2, bf2, out, batch, nullptr, NGRAPH, 128, 1024);
}